// Round 7
// baseline (128.550 us; speedup 1.0000x reference)
//
#include <hip/hip_runtime.h>
#include <hip/hip_bf16.h>
#include <math.h>

constexpr int D      = 2048;
constexpr int NE     = 64;
constexpr int TOKENS = 16384;   // 4*4096
constexpr int TPB    = 32;      // tokens per block
constexpr int NWAVE  = 8;       // k-split waves (wave w owns k-slice w)
constexpr int KSLICE = D / NWAVE;   // 256 floats = 1 KB per row per slice
constexpr int KC     = 32;      // k per MFMA step
constexpr int NKC    = KSLICE / KC; // 8
constexpr int PAD    = 66;

typedef __attribute__((ext_vector_type(8))) short bf16x8;
typedef __attribute__((ext_vector_type(4))) float f32x4;

static __device__ inline unsigned short f2bf_u(float x) {
  __hip_bfloat16 h = __float2bfloat16(x);   // RNE
  unsigned short u; __builtin_memcpy(&u, &h, 2); return u;
}
static __device__ inline float bfu2f(unsigned short u) {
  __hip_bfloat16 h; __builtin_memcpy(&h, &u, 2);
  return __bfloat162float(h);
}

// split 8 f32 into hi/lo bf16 — bit-identical to rounds 2-6
static __device__ inline void cvt_hilo(const float* f, bf16x8& hi, bf16x8& lo) {
#pragma unroll
  for (int j = 0; j < 8; ++j) {
    unsigned short h = f2bf_u(f[j]);
    float hf = bfu2f(h);
    unsigned short lw = f2bf_u(f[j] - hf);
    hi[j] = (short)h;
    lo[j] = (short)lw;
  }
}

// pre-kernel: W (64x2048 f32) -> Whi/Wlo bf16 (bit-identical split), single copy
__global__ __launch_bounds__(256)
void prep_w(const float* __restrict__ W, unsigned short* __restrict__ Whi,
            unsigned short* __restrict__ Wlo) {
  const int i = (blockIdx.x * 256 + threadIdx.x) * 4;
  float4 v = *reinterpret_cast<const float4*>(W + i);
  float f[4] = {v.x, v.y, v.z, v.w};
#pragma unroll
  for (int j = 0; j < 4; ++j) {
    unsigned short h = f2bf_u(f[j]);
    float hf = bfu2f(h);
    Whi[i + j] = h;
    Wlo[i + j] = f2bf_u(f[j] - hf);
  }
}

__global__ __launch_bounds__(512, 2)
void router_main(const float* __restrict__ X,
                 const unsigned short* __restrict__ Whi,
                 const unsigned short* __restrict__ Wlo,
                 const float* __restrict__ bias,
                 float* __restrict__ out) {
  // 64 KB: double-buffered X tile [2][32 rows][256 floats]; reduce phase overlays it
  __shared__ __align__(16) char smem[2 * 32 * 1024];
  float (*buf)[32][KSLICE] = reinterpret_cast<float (*)[32][KSLICE]>(smem);
  float (*red)[TPB][PAD]   = reinterpret_cast<float (*)[TPB][PAD]>(smem);  // [4][32][66]
  __shared__ int   i1s[TPB], i2s[TPB];
  __shared__ float p1s[TPB], p2s[TPB];

  const int t  = threadIdx.x;
  const int w  = t >> 6;        // wave id = k-slice / compute-chunk id
  const int l  = t & 63;
  const int lm = l & 15;        // M-row / N-col in 16x16 tile
  const int lk = l >> 4;        // k-group -> k offset lk*8
  const int tok0 = blockIdx.x * TPB;

  f32x4 acc[2][4];
#pragma unroll
  for (int m = 0; m < 2; ++m)
#pragma unroll
    for (int n = 0; n < 4; ++n) acc[m][n] = (f32x4){0.f, 0.f, 0.f, 0.f};

  const unsigned short* whp = Whi + (size_t)lm * D + w * KSLICE + lk * 8;
  const unsigned short* wlp = Wlo + (size_t)lm * D + w * KSLICE + lk * 8;

  // stage chunk cc into buf[pb]: wave w stages rows 4w..4w+3; one wave-instr = one
  // full 1 KB row slice, CONTIGUOUS in global (DRAM-friendly); LDS write XOR-swizzled.
  auto stage = [&](int pb, int cc) {
#pragma unroll
    for (int i = 0; i < 4; ++i) {
      const int r = 4 * w + i;
      float4 v = *reinterpret_cast<const float4*>(
          X + (size_t)(tok0 + r) * D + cc * KSLICE + l * 4);
      char* rowbase = reinterpret_cast<char*>(&buf[pb][r][0]);
      *reinterpret_cast<float4*>(rowbase + ((l * 16) ^ ((r & 7) << 4))) = v;
    }
  };

  stage(0, 0);
  __syncthreads();

#pragma unroll 1
  for (int c = 0; c < NWAVE; ++c) {
    if (c < NWAVE - 1) stage((c + 1) & 1, c + 1);   // overlap next-chunk staging
    if (w == c) {
      const int pb = c & 1;
#pragma unroll
      for (int kc = 0; kc < NKC; ++kc) {
        const int ko = kc * KC;
        bf16x8 bh[4], bl[4];
#pragma unroll
        for (int n = 0; n < 4; ++n) {
          bh[n] = *reinterpret_cast<const bf16x8*>(whp + (size_t)n * 16 * D + ko);
          bl[n] = *reinterpret_cast<const bf16x8*>(wlp + (size_t)n * 16 * D + ko);
        }
#pragma unroll
        for (int m = 0; m < 2; ++m) {               // same m, n, hh/hl/lh/ll order as R2-6
          const int rr = m * 16 + lm;
          const int s  = (rr & 7) << 4;
          const char* rowbase = reinterpret_cast<const char*>(&buf[pb][rr][0]);
          const int b = kc * 128 + lk * 32;
          float f[8];
          *reinterpret_cast<float4*>(&f[0]) =
              *reinterpret_cast<const float4*>(rowbase + ((b) ^ s));
          *reinterpret_cast<float4*>(&f[4]) =
              *reinterpret_cast<const float4*>(rowbase + ((b + 16) ^ s));
          bf16x8 ah, al;
          cvt_hilo(f, ah, al);
#pragma unroll
          for (int n = 0; n < 4; ++n) {
            acc[m][n] = __builtin_amdgcn_mfma_f32_16x16x32_bf16(ah, bh[n], acc[m][n], 0, 0, 0);
            acc[m][n] = __builtin_amdgcn_mfma_f32_16x16x32_bf16(ah, bl[n], acc[m][n], 0, 0, 0);
            acc[m][n] = __builtin_amdgcn_mfma_f32_16x16x32_bf16(al, bh[n], acc[m][n], 0, 0, 0);
            acc[m][n] = __builtin_amdgcn_mfma_f32_16x16x32_bf16(al, bl[n], acc[m][n], 0, 0, 0);
          }
        }
      }
    }
    __syncthreads();   // staged chunk c+1 visible; buf[c&1] free for reuse
  }

  // ---- two-batch cross-wave reduce (overlaid on buf); bias + w0+...+w7 order exact ----
  const int rtok = t >> 4;          // 0..31
  const int re0  = (t & 15) * 4;    // 0..60
  float s[4];

  if (w < 4) {                       // batch 1: waves 0..3 stash
#pragma unroll
    for (int m = 0; m < 2; ++m)
#pragma unroll
      for (int n = 0; n < 4; ++n)
#pragma unroll
        for (int j = 0; j < 4; ++j)
          red[w][m * 16 + lk * 4 + j][n * 16 + lm] = acc[m][n][j];
  }
  __syncthreads();
#pragma unroll
  for (int q = 0; q < 4; ++q) {
    const int e = re0 + q;
    float v = bias[e];
#pragma unroll
    for (int ww = 0; ww < 4; ++ww) v += red[ww][rtok][e];
    s[q] = v;
  }
  __syncthreads();
  if (w >= 4) {                      // batch 2: waves 4..7 stash (same buffer)
#pragma unroll
    for (int m = 0; m < 2; ++m)
#pragma unroll
      for (int n = 0; n < 4; ++n)
#pragma unroll
        for (int j = 0; j < 4; ++j)
          red[w - 4][m * 16 + lk * 4 + j][n * 16 + lm] = acc[m][n][j];
  }
  __syncthreads();
#pragma unroll
  for (int q = 0; q < 4; ++q) {
    const int e = re0 + q;
    float v = s[q];
#pragma unroll
    for (int ww = 0; ww < 4; ++ww) v += red[ww][rtok][e];
    red[0][rtok][e] = v;             // 1:1 slot ownership
  }
  __syncthreads();

  // ---- top-2 + softmax weights (threads 0..31, one token each) ----
  if (t < TPB) {
    float m1 = -INFINITY, m2 = -INFINITY;
    int j1 = 0, j2 = 0;
    for (int e = 0; e < NE; ++e) {
      const float v = red[0][t][e];
      if (v > m1) { m2 = m1; j2 = j1; m1 = v; j1 = e; }     // strict >: lax.top_k tie-break
      else if (v > m2) { m2 = v; j2 = e; }
    }
    const float e2  = expf(m2 - m1);
    const float inv = 1.0f / (1.0f + e2);
    i1s[t] = j1; i2s[t] = j2;
    p1s[t] = inv; p2s[t] = e2 * inv;
    float* oidx = out + (size_t)TOKENS * NE + (size_t)(tok0 + t) * 2;
    oidx[0] = (float)j1;
    oidx[1] = (float)j2;
  }
  __syncthreads();

  // ---- coalesced sf write: 512 thr -> (token = t>>4, experts 4*(t&15)..+3) ----
  {
    const int tok = t >> 4;
    const int e0  = (t & 15) * 4;
    const int j1 = i1s[tok], j2 = i2s[tok];
    const float pa = p1s[tok], pb2 = p2s[tok];
    float vv[4];
#pragma unroll
    for (int q = 0; q < 4; ++q) {
      const int e = e0 + q;
      vv[q] = (e == j1) ? pa : ((e == j2) ? pb2 : 0.f);
    }
    *reinterpret_cast<float4*>(out + (size_t)(tok0 + tok) * NE + e0) =
        make_float4(vv[0], vv[1], vv[2], vv[3]);
  }
}

extern "C" void kernel_launch(void* const* d_in, const int* in_sizes, int n_in,
                              void* d_out, int out_size, void* d_ws, size_t ws_size,
                              hipStream_t stream) {
  const float* X = (const float*)d_in[0];
  const float* W = (const float*)d_in[1];
  const float* B = (const float*)d_in[2];
  float* out = (float*)d_out;

  unsigned short* Whi = (unsigned short*)d_ws;     // 256 KB
  unsigned short* Wlo = Whi + (size_t)NE * D;      // 256 KB

  prep_w<<<dim3(NE * D / (256 * 4)), dim3(256), 0, stream>>>(W, Whi, Wlo);
  router_main<<<dim3(TOKENS / TPB), dim3(512), 0, stream>>>(X, Whi, Wlo, B, out);
}

// Round 8
// 47.837 us; speedup vs baseline: 2.6872x; 2.6872x over previous
//
#include <hip/hip_runtime.h>
#include <hip/hip_bf16.h>
#include <math.h>

constexpr int D      = 2048;
constexpr int NE     = 64;
constexpr int TOKENS = 16384;   // 4*4096
constexpr int TPB    = 64;      // tokens per block -> W traffic = 512KB * 256 blocks = 128 MB
constexpr int NBLK   = TOKENS / TPB;   // 256 = 1 block/CU, no tail
constexpr int NWAVE  = 8;       // k-split waves
constexpr int KSLICE = D / NWAVE;   // 256
constexpr int KC     = 32;      // k per MFMA step
constexpr int NKC    = KSLICE / KC; // 8
constexpr int PAD    = 66;
constexpr int NM     = TPB / 16;    // 4 m-tiles per wave

typedef __attribute__((ext_vector_type(8))) short bf16x8;
typedef __attribute__((ext_vector_type(4))) float f32x4;

static __device__ inline unsigned short f2bf_u(float x) {
  __hip_bfloat16 h = __float2bfloat16(x);   // RNE
  unsigned short u; __builtin_memcpy(&u, &h, 2); return u;
}
static __device__ inline float bfu2f(unsigned short u) {
  __hip_bfloat16 h; __builtin_memcpy(&h, &u, 2);
  return __bfloat162float(h);
}

// split 8 f32 into hi/lo bf16 — bit-identical to rounds 2-7
static __device__ inline void cvt_hilo(const float* f, bf16x8& hi, bf16x8& lo) {
#pragma unroll
  for (int j = 0; j < 8; ++j) {
    unsigned short h = f2bf_u(f[j]);
    float hf = bfu2f(h);
    unsigned short lw = f2bf_u(f[j] - hf);
    hi[j] = (short)h;
    lo[j] = (short)lw;
  }
}

// pre-kernel: W (64x2048 f32) -> Whi/Wlo bf16 (bit-identical split)
__global__ __launch_bounds__(256)
void prep_w(const float* __restrict__ W, unsigned short* __restrict__ Whi,
            unsigned short* __restrict__ Wlo) {
  const int i = (blockIdx.x * 256 + threadIdx.x) * 4;
  float4 v = *reinterpret_cast<const float4*>(W + i);
  float f[4] = {v.x, v.y, v.z, v.w};
#pragma unroll
  for (int j = 0; j < 4; ++j) {
    unsigned short h = f2bf_u(f[j]);
    float hf = bfu2f(h);
    Whi[i + j] = h;
    Wlo[i + j] = f2bf_u(f[j] - hf);
  }
}

__global__ __launch_bounds__(512, 2)
void router_main(const float* __restrict__ X,
                 const unsigned short* __restrict__ Whi,
                 const unsigned short* __restrict__ Wlo,
                 const float* __restrict__ bias,
                 float* __restrict__ out) {
  __shared__ float red[4][TPB][PAD];   // 67.6 KB, used twice (waves 0-3 then 4-7)
  __shared__ int   i1s[TPB], i2s[TPB];
  __shared__ float p1s[TPB], p2s[TPB];

  const int t  = threadIdx.x;
  const int w  = t >> 6;        // wave id = k-slice
  const int l  = t & 63;
  const int lm = l & 15;        // M-row / N-col in 16x16 tile
  const int lk = l >> 4;        // k-group -> k offset lk*8
  // XCD swizzle: xcd = bid%8 gets contiguous token range (16 MB of X per XCD-L2)
  const int tile = (blockIdx.x & 7) * (NBLK / 8) + (blockIdx.x >> 3);
  const int tok0 = tile * TPB;

  f32x4 acc[NM][4];
#pragma unroll
  for (int m = 0; m < NM; ++m)
#pragma unroll
    for (int n = 0; n < 4; ++n) acc[m][n] = (f32x4){0.f, 0.f, 0.f, 0.f};

  const unsigned short* whp = Whi + (size_t)lm * D + w * KSLICE + lk * 8;
  const unsigned short* wlp = Wlo + (size_t)lm * D + w * KSLICE + lk * 8;
  const float* xr[NM];
#pragma unroll
  for (int m = 0; m < NM; ++m)
    xr[m] = X + (size_t)(tok0 + m * 16 + lm) * D + w * KSLICE + lk * 8;

  // X staging, double-buffered one kc ahead
  float4 c0[NM], c1[NM];
#pragma unroll
  for (int m = 0; m < NM; ++m) {
    c0[m] = *reinterpret_cast<const float4*>(xr[m]);
    c1[m] = *reinterpret_cast<const float4*>(xr[m] + 4);
  }

#pragma unroll
  for (int kc = 0; kc < NKC; ++kc) {
    const int ko = kc * KC;

    // batched B loads: 8 independent dwordx4 in flight
    bf16x8 bh[4], bl[4];
#pragma unroll
    for (int n = 0; n < 4; ++n) {
      bh[n] = *reinterpret_cast<const bf16x8*>(whp + (size_t)n * 16 * D + ko);
      bl[n] = *reinterpret_cast<const bf16x8*>(wlp + (size_t)n * 16 * D + ko);
    }

    // prefetch next-kc X for all 4 m-tiles (8 more loads in flight)
    float4 n0[NM], n1[NM];
    if (kc < NKC - 1) {
#pragma unroll
      for (int m = 0; m < NM; ++m) {
        n0[m] = *reinterpret_cast<const float4*>(xr[m] + (kc + 1) * KC);
        n1[m] = *reinterpret_cast<const float4*>(xr[m] + (kc + 1) * KC + 4);
      }
    }

#pragma unroll
    for (int m = 0; m < NM; ++m) {            // same kc / hh,hl,lh,ll order as rounds 2-7
      float f[8];
      *reinterpret_cast<float4*>(&f[0]) = c0[m];
      *reinterpret_cast<float4*>(&f[4]) = c1[m];
      bf16x8 ah, al;
      cvt_hilo(f, ah, al);
#pragma unroll
      for (int n = 0; n < 4; ++n) {
        acc[m][n] = __builtin_amdgcn_mfma_f32_16x16x32_bf16(ah, bh[n], acc[m][n], 0, 0, 0);
        acc[m][n] = __builtin_amdgcn_mfma_f32_16x16x32_bf16(ah, bl[n], acc[m][n], 0, 0, 0);
        acc[m][n] = __builtin_amdgcn_mfma_f32_16x16x32_bf16(al, bh[n], acc[m][n], 0, 0, 0);
        acc[m][n] = __builtin_amdgcn_mfma_f32_16x16x32_bf16(al, bl[n], acc[m][n], 0, 0, 0);
      }
    }
    if (kc < NKC - 1) {
#pragma unroll
      for (int m = 0; m < NM; ++m) { c0[m] = n0[m]; c1[m] = n1[m]; }
    }
  }

  // ---- two-batch cross-wave reduce; preserves bias + w0+...+w7 order exactly ----
  const int rtok = t >> 3;          // 0..63
  const int re0  = (t & 7) * 8;     // 0..56
  float s[8];

  if (w < 4) {                       // batch 1: waves 0..3 stash
#pragma unroll
    for (int m = 0; m < NM; ++m)
#pragma unroll
      for (int n = 0; n < 4; ++n)
#pragma unroll
        for (int j = 0; j < 4; ++j)
          red[w][m * 16 + lk * 4 + j][n * 16 + lm] = acc[m][n][j];
  }
  __syncthreads();
#pragma unroll
  for (int q = 0; q < 8; ++q) {
    const int e = re0 + q;
    float v = bias[e];
#pragma unroll
    for (int ww = 0; ww < 4; ++ww) v += red[ww][rtok][e];
    s[q] = v;
  }
  __syncthreads();
  if (w >= 4) {                      // batch 2: waves 4..7 stash (same buffer)
#pragma unroll
    for (int m = 0; m < NM; ++m)
#pragma unroll
      for (int n = 0; n < 4; ++n)
#pragma unroll
        for (int j = 0; j < 4; ++j)
          red[w - 4][m * 16 + lk * 4 + j][n * 16 + lm] = acc[m][n][j];
  }
  __syncthreads();
#pragma unroll
  for (int q = 0; q < 8; ++q) {
    const int e = re0 + q;
    float v = s[q];
#pragma unroll
    for (int ww = 0; ww < 4; ++ww) v += red[ww][rtok][e];
    red[0][rtok][e] = v;             // 1:1 slot ownership
  }
  __syncthreads();

  // ---- top-2 + softmax weights (threads 0..63, one token each) ----
  if (t < TPB) {
    float m1 = -INFINITY, m2 = -INFINITY;
    int j1 = 0, j2 = 0;
    for (int e = 0; e < NE; ++e) {
      const float v = red[0][t][e];
      if (v > m1) { m2 = m1; j2 = j1; m1 = v; j1 = e; }     // strict >: lax.top_k tie-break
      else if (v > m2) { m2 = v; j2 = e; }
    }
    const float e2  = expf(m2 - m1);
    const float inv = 1.0f / (1.0f + e2);
    i1s[t] = j1; i2s[t] = j2;
    p1s[t] = inv; p2s[t] = e2 * inv;
    float* oidx = out + (size_t)TOKENS * NE + (size_t)(tok0 + t) * 2;
    oidx[0] = (float)j1;
    oidx[1] = (float)j2;
  }
  __syncthreads();

  // ---- coalesced sf write: 512 thr -> (token = t>>3, experts 8*(t&7)..+7) ----
  {
    const int tok = t >> 3;
    const int e0  = (t & 7) * 8;
    const int j1 = i1s[tok], j2 = i2s[tok];
    const float pa = p1s[tok], pb2 = p2s[tok];
    float vv[8];
#pragma unroll
    for (int q = 0; q < 8; ++q) {
      const int e = e0 + q;
      vv[q] = (e == j1) ? pa : ((e == j2) ? pb2 : 0.f);
    }
    float* obase = out + (size_t)(tok0 + tok) * NE + e0;
    *reinterpret_cast<float4*>(obase)     = make_float4(vv[0], vv[1], vv[2], vv[3]);
    *reinterpret_cast<float4*>(obase + 4) = make_float4(vv[4], vv[5], vv[6], vv[7]);
  }
}

extern "C" void kernel_launch(void* const* d_in, const int* in_sizes, int n_in,
                              void* d_out, int out_size, void* d_ws, size_t ws_size,
                              hipStream_t stream) {
  const float* X = (const float*)d_in[0];
  const float* W = (const float*)d_in[1];
  const float* B = (const float*)d_in[2];
  float* out = (float*)d_out;

  unsigned short* Whi = (unsigned short*)d_ws;     // 256 KB
  unsigned short* Wlo = Whi + (size_t)NE * D;      // 256 KB

  prep_w<<<dim3(NE * D / (256 * 4)), dim3(256), 0, stream>>>(W, Whi, Wlo);
  router_main<<<dim3(NBLK), dim3(512), 0, stream>>>(X, Whi, Wlo, B, out);
}